// Round 2
// baseline (350.604 us; speedup 1.0000x reference)
//
#include <hip/hip_runtime.h>

#define NG   256   // graphs (= grid)
#define NP   512   // nodes per graph
#define EPG  8192  // edges per graph
#define FDIM 128
#define CEMB 32

#define STA 33     // bufA stride (floats): (v+j)%32 -> conflict-free row reads
#define STB 36     // bufB stride (floats): 16B aligned, b128 groups (v+cq)%8 spread

// ---- LDS layout (bytes) ----
#define OFF_BUFA 0
#define OFF_BUFB (NP*STA*4)              // 67584
#define OFF_CSR  (OFF_BUFB + NP*STB*4)   // 141312
#define OFF_OFFS (OFF_CSR + EPG*2)       // 157696  (u16 offs[513], padded)
#define OFF_CNT  (OFF_OFFS + 1032)       // 158728  (u32[512])
#define OFF_NORM (OFF_CNT + NP*4)        // 160776  (f32[512])
#define SMEM_SZ  (OFF_NORM + NP*4)       // 162824 <= 163840

// overlays in the CSR region (dead after layer-3 aggregation)
#define OFF_KEY  OFF_CSR
#define OFF_IDX  (OFF_CSR + 2048)
#define OFF_C1   (OFF_CSR + 4096)   // f32[16*64]
#define OFF_P    (OFF_CSR + 8192)   // f32[16*32]
#define OFF_C2   (OFF_CSR + 10240)  // f32[32*28] = flat[896]
#define OFF_HID  (OFF_CSR + 13824)  // f32[128]

__global__ __launch_bounds__(512) void dgcnn_fused(
    const float* __restrict__ x,
    const float* __restrict__ W0, const float* __restrict__ b0,
    const float* __restrict__ W1, const float* __restrict__ b1,
    const float* __restrict__ W2, const float* __restrict__ b2,
    const float* __restrict__ W3, const float* __restrict__ b3,
    const float* __restrict__ c1w, const float* __restrict__ c1b,
    const float* __restrict__ c2w, const float* __restrict__ c2b,
    const float* __restrict__ d1w, const float* __restrict__ d1b,
    const float* __restrict__ d2w, const float* __restrict__ d2b,
    const int* __restrict__ esrc, const int* __restrict__ edst,
    float* __restrict__ hs1, float* __restrict__ hs2,
    float* __restrict__ out)
{
  extern __shared__ char smem[];
  float*          bufA  = (float*)(smem + OFF_BUFA);
  float*          bufB  = (float*)(smem + OFF_BUFB);
  unsigned short* csr   = (unsigned short*)(smem + OFF_CSR);
  unsigned short* offs  = (unsigned short*)(smem + OFF_OFFS);
  unsigned int*   cnt   = (unsigned int*)(smem + OFF_CNT);
  float*          normv = (float*)(smem + OFF_NORM);
  unsigned int*   degc  = (unsigned int*)(smem + OFF_NORM); // alias (u32 counts first)
  float*          lin3S = (float*)(smem + OFF_CNT);         // alias (after cursors dead)
  float*          keyA  = (float*)(smem + OFF_KEY);
  unsigned int*   idxA  = (unsigned int*)(smem + OFF_IDX);
  float*          featS = bufB;                             // [64][100] after layers
  float*          c1s   = (float*)(smem + OFF_C1);
  float*          ps    = (float*)(smem + OFF_P);
  float*          c2s   = (float*)(smem + OFF_C2);
  float*          hids  = (float*)(smem + OFF_HID);

  const int g    = blockIdx.x;
  const int tid  = threadIdx.x;
  const int lane = tid & 63;
  const int wv   = tid >> 6;
  const int nb   = g * NP;

  // ---------- phase 0: zero counters ----------
  cnt[tid]  = 0u;
  degc[tid] = 0u;
  __syncthreads();

  // ---------- phase 1: load edges (held in regs), count deg(src) & indeg(dst) ----------
  int es[16], ed[16];
  {
    const int eb = g * EPG;
#pragma unroll
    for (int i = 0; i < 16; i++) {
      const int e = eb + tid + i * 512;
      es[i] = esrc[e] - nb;
      ed[i] = edst[e] - nb;
    }
#pragma unroll
    for (int i = 0; i < 16; i++) {
      atomicAdd(&degc[es[i]], 1u);
      atomicAdd(&cnt[ed[i]], 1u);
    }
  }
  __syncthreads();

  // ---------- phase 2: norm = 1/(deg+1); inclusive scan cnt -> offs; zero cursors ----------
  const unsigned my_deg = degc[tid];
  unsigned v_scan = cnt[tid];
  for (int off = 1; off < NP; off <<= 1) {
    const unsigned o = (tid >= off) ? cnt[tid - off] : 0u;
    __syncthreads();
    v_scan += o;
    cnt[tid] = v_scan;
    __syncthreads();
  }
  offs[tid + 1] = (unsigned short)v_scan;
  if (tid == 0) offs[0] = 0;
  normv[tid] = 1.0f / (float)(my_deg + 1u);   // overwrites degc (already read)
  cnt[tid] = 0u;                              // cursor
  __syncthreads();

  // ---------- phase 3: fill CSR (src lists bucketed by dst) ----------
#pragma unroll
  for (int i = 0; i < 16; i++) {
    const unsigned pos = (unsigned)offs[ed[i]] + atomicAdd(&cnt[ed[i]], 1u);
    csr[pos] = (unsigned short)es[i];
  }
  __syncthreads();

  // ---------- phase 4: lin0 = x @ W0^T + b0  (thread = node; W0 via scalar loads) ----------
  {
    const float4* xr = (const float4*)(x + (size_t)(nb + tid) * FDIM);
    float acc[32];
#pragma unroll
    for (int c = 0; c < 32; c++) acc[c] = b0[c];
#pragma unroll 4
    for (int k0 = 0; k0 < 32; k0++) {
      const float4 xv = xr[k0];
#pragma unroll
      for (int c = 0; c < 32; c++) {
        const float* wr = W0 + c * FDIM + k0 * 4;
        acc[c] = fmaf(xv.x, wr[0], acc[c]);
        acc[c] = fmaf(xv.y, wr[1], acc[c]);
        acc[c] = fmaf(xv.z, wr[2], acc[c]);
        acc[c] = fmaf(xv.w, wr[3], acc[c]);
      }
    }
    float4* br = (float4*)(bufB + tid * STB);
#pragma unroll
    for (int cq = 0; cq < 8; cq++)
      br[cq] = make_float4(acc[cq*4+0], acc[cq*4+1], acc[cq*4+2], acc[cq*4+3]);
  }
  __syncthreads();

  // aggregate: bufA[v] = tanh(norm[v] * (bufB[v] + sum_{in-edges} bufB[src]))
  auto do_agg = [&]() {
    const int v = tid;
    float4 A[8];
    const float4* sb = (const float4*)(bufB + v * STB);
#pragma unroll
    for (int cq = 0; cq < 8; cq++) A[cq] = sb[cq];
    const int e0 = offs[v], e1 = offs[v + 1];
    for (int e = e0; e < e1; e++) {
      const int s = csr[e];
      const float4* rb = (const float4*)(bufB + s * STB);
#pragma unroll
      for (int cq = 0; cq < 8; cq++) {
        const float4 r = rb[cq];
        A[cq].x += r.x; A[cq].y += r.y; A[cq].z += r.z; A[cq].w += r.w;
      }
    }
    const float nv = normv[v];
    float* ar = bufA + v * STA;
#pragma unroll
    for (int cq = 0; cq < 8; cq++) {
      ar[cq*4+0] = tanhf(A[cq].x * nv);
      ar[cq*4+1] = tanhf(A[cq].y * nv);
      ar[cq*4+2] = tanhf(A[cq].z * nv);
      ar[cq*4+3] = tanhf(A[cq].w * nv);
    }
  };

  // lin: bufB[v] = bufA[v] @ W^T + b  (32x32, W via scalar loads)
  auto do_lin = [&](const float* __restrict__ W, const float* __restrict__ b) {
    float h[32];
    const float* ar = bufA + tid * STA;
#pragma unroll
    for (int j = 0; j < 32; j++) h[j] = ar[j];
    float acc[32];
#pragma unroll
    for (int c = 0; c < 32; c++) acc[c] = b[c];
#pragma unroll
    for (int j = 0; j < 32; j++) {
#pragma unroll
      for (int c = 0; c < 32; c++)
        acc[c] = fmaf(h[j], W[c * 32 + j], acc[c]);
    }
    float4* br = (float4*)(bufB + tid * STB);
#pragma unroll
    for (int cq = 0; cq < 8; cq++)
      br[cq] = make_float4(acc[cq*4+0], acc[cq*4+1], acc[cq*4+2], acc[cq*4+3]);
  };

  // coalesced spill of bufA (512x32) to global scratch
  auto spill = [&](float* dst) {
#pragma unroll
    for (int i = 0; i < 32; i++) {
      const int idx = tid + i * 512;
      dst[(size_t)g * (NP * 32) + idx] = bufA[(idx >> 5) * STA + (idx & 31)];
    }
  };

  // ---------- layers 0..2 ----------
  do_agg();                 // h1 -> bufA
  __syncthreads();
  spill(hs1);
  do_lin(W1, b1);           // lin1 -> bufB
  __syncthreads();
  do_agg();                 // h2 -> bufA
  __syncthreads();
  spill(hs2);
  do_lin(W2, b2);           // lin2 -> bufB
  __syncthreads();
  do_agg();                 // h3 -> bufA (kept in LDS)

  // ---------- layer 3 (1 channel): double-precision accumulation (sort key!) ----------
  {
    const float* ar = bufA + tid * STA;   // own row, written by self
    double a = (double)b3[0];
#pragma unroll
    for (int j = 0; j < 32; j++) a = fma((double)ar[j], (double)W3[j], a);
    lin3S[tid] = (float)a;                // fp32 boundary, as in reference
  }
  __syncthreads();
  float h4;
  {
    double a = (double)lin3S[tid];
    const int e0 = offs[tid], e1 = offs[tid + 1];
    for (int e = e0; e < e1; e++) a += (double)lin3S[csr[e]];
    a *= (double)normv[tid];
    h4 = tanhf((float)a);                 // fp32 boundary then exact tanh
  }
  __syncthreads();                        // all csr/lin3S reads done; csr region now reusable
  keyA[tid] = h4;
  idxA[tid] = (unsigned)tid;

  // ---------- bitonic sort: desc by value, asc index (matches stable argsort of -g) ----------
  for (int k = 2; k <= NP; k <<= 1) {
    for (int j = k >> 1; j > 0; j >>= 1) {
      __syncthreads();
      const int i = tid;
      const int l = i ^ j;
      if (l > i) {
        const float    ki = keyA[i], kl = keyA[l];
        const unsigned ii = idxA[i], il = idxA[l];
        const bool iBeforeL = (ki > kl) || (ki == kl && ii < il);
        const bool doSwap = ((i & k) == 0) ? (!iBeforeL) : iBeforeL;
        if (doSwap) {
          keyA[i] = kl; keyA[l] = ki;
          idxA[i] = il; idxA[l] = ii;
        }
      }
    }
  }
  __syncthreads();

  // ---------- gather top-64 features [64][97] into featS (bufB region) ----------
  {
    const int k = tid >> 3, q = tid & 7;
    const int node = (int)idxA[k];
    const size_t go = (size_t)g * (NP * 32) + (size_t)node * 32;
    const float4 f1 = *((const float4*)(hs1 + go) + q);
    const float4 f2 = *((const float4*)(hs2 + go) + q);
    float4 f3;
    const float* a3 = bufA + node * STA + q * 4;
    f3.x = a3[0]; f3.y = a3[1]; f3.z = a3[2]; f3.w = a3[3];
    float* fr = featS + k * 100;
    *((float4*)(fr)      + q) = f1;
    *((float4*)(fr + 32) + q) = f2;
    *((float4*)(fr + 64) + q) = f3;
    if (q == 0) fr[96] = keyA[k];
  }
  __syncthreads();

  // ---------- conv1 (per-node linear over 97), double acc : wave = 2 out channels ----------
  {
    const int o0 = __builtin_amdgcn_readfirstlane(wv) * 2;
    const int o1 = o0 + 1;
    const int k  = lane;
    const float* fr  = featS + k * 100;
    const float* w0r = c1w + o0 * 97;
    const float* w1r = c1w + o1 * 97;
    double a0 = (double)c1b[o0], a1 = (double)c1b[o1];
#pragma unroll
    for (int d4 = 0; d4 < 24; d4++) {
      const float4 fv = *(const float4*)(fr + d4 * 4);
      a0 = fma((double)fv.x, (double)w0r[d4*4+0], a0);
      a0 = fma((double)fv.y, (double)w0r[d4*4+1], a0);
      a0 = fma((double)fv.z, (double)w0r[d4*4+2], a0);
      a0 = fma((double)fv.w, (double)w0r[d4*4+3], a0);
      a1 = fma((double)fv.x, (double)w1r[d4*4+0], a1);
      a1 = fma((double)fv.y, (double)w1r[d4*4+1], a1);
      a1 = fma((double)fv.z, (double)w1r[d4*4+2], a1);
      a1 = fma((double)fv.w, (double)w1r[d4*4+3], a1);
    }
    const double f96 = (double)fr[96];
    a0 = fma(f96, (double)w0r[96], a0);
    a1 = fma(f96, (double)w1r[96], a1);
    c1s[o0 * 64 + k] = fmaxf((float)a0, 0.f);
    c1s[o1 * 64 + k] = fmaxf((float)a1, 0.f);
  }
  __syncthreads();

  // ---------- maxpool(2,2) ----------
  {
    const int o = tid >> 5, jj = tid & 31;
    ps[o * 32 + jj] = fmaxf(c1s[o * 64 + 2 * jj], c1s[o * 64 + 2 * jj + 1]);
  }
  __syncthreads();

  // ---------- conv2 (k=5, valid), double acc: wave = 4 out channels, lanes = t ----------
  {
    const int ob = __builtin_amdgcn_readfirstlane(wv);
    const int t = lane;
    if (t < 28) {
      double a0 = 0., a1 = 0., a2 = 0., a3 = 0.;
      for (int i = 0; i < 16; i++) {
#pragma unroll
        for (int r = 0; r < 5; r++) {
          const double pv = (double)ps[i * 32 + t + r];
          a0 = fma(pv, (double)c2w[((ob     ) * 16 + i) * 5 + r], a0);
          a1 = fma(pv, (double)c2w[((ob +  8) * 16 + i) * 5 + r], a1);
          a2 = fma(pv, (double)c2w[((ob + 16) * 16 + i) * 5 + r], a2);
          a3 = fma(pv, (double)c2w[((ob + 24) * 16 + i) * 5 + r], a3);
        }
      }
      c2s[(ob     ) * 28 + t] = fmaxf((float)(a0 + (double)c2b[ob     ]), 0.f);
      c2s[(ob +  8) * 28 + t] = fmaxf((float)(a1 + (double)c2b[ob +  8]), 0.f);
      c2s[(ob + 16) * 28 + t] = fmaxf((float)(a2 + (double)c2b[ob + 16]), 0.f);
      c2s[(ob + 24) * 28 + t] = fmaxf((float)(a3 + (double)c2b[ob + 24]), 0.f);
    }
  }
  __syncthreads();

  // ---------- d1: 896 -> 128, relu; double acc; wave computes 16 outputs ----------
  {
    float fl[14];
#pragma unroll
    for (int j = 0; j < 14; j++) fl[j] = c2s[lane + j * 64];  // flat[896]
    const int h0 = __builtin_amdgcn_readfirstlane(wv) * 16;
    for (int hh = 0; hh < 16; hh++) {
      const int h = h0 + hh;
      const float* wr = d1w + (size_t)h * 896;
      double a = 0.;
#pragma unroll
      for (int j = 0; j < 14; j++) a = fma((double)fl[j], (double)wr[lane + j * 64], a);
#pragma unroll
      for (int m = 32; m > 0; m >>= 1) a += __shfl_xor(a, m, 64);
      if (lane == 0) hids[h] = fmaxf((float)(a + (double)d1b[h]), 0.f);
    }
  }
  __syncthreads();

  // ---------- d2: 128 -> 10 (no relu), double acc ----------
  if (tid < 10) {
    const float* wr = d2w + tid * 128;
    double a = (double)d2b[tid];
#pragma unroll 8
    for (int h = 0; h < 128; h++) a = fma((double)hids[h], (double)wr[h], a);
    out[g * 10 + tid] = (float)a;
  }
}

extern "C" void kernel_launch(void* const* d_in, const int* in_sizes, int n_in,
                              void* d_out, int out_size, void* d_ws, size_t ws_size,
                              hipStream_t stream) {
  const float* x   = (const float*)d_in[0];
  const float* W0  = (const float*)d_in[1];
  const float* b0  = (const float*)d_in[2];
  const float* W1  = (const float*)d_in[3];
  const float* b1  = (const float*)d_in[4];
  const float* W2  = (const float*)d_in[5];
  const float* b2  = (const float*)d_in[6];
  const float* W3  = (const float*)d_in[7];
  const float* b3  = (const float*)d_in[8];
  const float* c1w = (const float*)d_in[9];
  const float* c1b = (const float*)d_in[10];
  const float* c2w = (const float*)d_in[11];
  const float* c2b = (const float*)d_in[12];
  const float* d1w = (const float*)d_in[13];
  const float* d1b = (const float*)d_in[14];
  const float* d2w = (const float*)d_in[15];
  const float* d2b = (const float*)d_in[16];
  const int* esrc  = (const int*)d_in[17];
  const int* edst  = (const int*)d_in[18];

  float* hs1 = (float*)d_ws;                       // 256*512*32 f32 = 16 MB
  float* hs2 = hs1 + (size_t)NG * NP * 32;         // +16 MB
  float* outp = (float*)d_out;

  hipFuncSetAttribute(reinterpret_cast<const void*>(dgcnn_fused),
                      hipFuncAttributeMaxDynamicSharedMemorySize, SMEM_SZ);
  dgcnn_fused<<<NG, 512, SMEM_SZ, stream>>>(x, W0, b0, W1, b1, W2, b2, W3, b3,
                                            c1w, c1b, c2w, c2b, d1w, d1b, d2w, d2b,
                                            esrc, edst, hs1, hs2, outp);
}

// Round 3
// 335.750 us; speedup vs baseline: 1.0442x; 1.0442x over previous
//
#include <hip/hip_runtime.h>

#define NG   256   // graphs (= grid)
#define NP   512   // nodes per graph
#define EPG  8192  // edges per graph
#define FDIM 128
#define STB  34    // bufB stride (floats): 34%32=2 -> random-row b128 reads spread banks

// ---- LDS layout (bytes) ----
#define OFF_BUFB 0                         // f32[512*34] = 69632
#define OFF_CSR  69632                     // u16[8192]   = 16384
#define OFF_OFFS (OFF_CSR + 16384)         // 86016: u16[513] -> 1028
#define OFF_WT   (OFF_OFFS + 1028)         // 87044: u32[8] = 32
#define OFF_CUR  (OFF_WT + 32)             // 87076: u32[512] = 2048
#define OFF_DCNT (OFF_CUR + 2048)          // 89124: u32[512] = 2048
#define OFF_NRM  (OFF_DCNT + 2048)         // 91172: f32[512] = 2048
#define OFF_L3   (OFF_NRM + 2048)          // 93220: f32[512] = 2048
#define SMEM_SZ  (OFF_L3 + 2048)           // 95268  (<160 KiB)

// overlays: sort arrays live in dead CSR region; tail arrays in dead bufB region
#define OFF_KEY  OFF_CSR                   // f32[512]
#define OFF_IDX  (OFF_CSR + 2048)          // u32[512]
// featS = bufB floats [0 .. 97*64) ; tail after it (float offsets)
#define FO_C1   (97*64)                    // f32[16*64]
#define FO_P    (FO_C1 + 16*64)            // f32[16*32]
#define FO_C2   (FO_P + 16*32)             // f32[896]
#define FO_HID  (FO_C2 + 896)              // f32[128]

__global__ __launch_bounds__(1024, 4) void dgcnn_fused(
    const float* __restrict__ x,
    const float* __restrict__ W0, const float* __restrict__ b0,
    const float* __restrict__ W1, const float* __restrict__ b1,
    const float* __restrict__ W2, const float* __restrict__ b2,
    const float* __restrict__ W3, const float* __restrict__ b3,
    const float* __restrict__ c1w, const float* __restrict__ c1b,
    const float* __restrict__ c2w, const float* __restrict__ c2b,
    const float* __restrict__ d1w, const float* __restrict__ d1b,
    const float* __restrict__ d2w, const float* __restrict__ d2b,
    const int* __restrict__ esrc, const int* __restrict__ edst,
    float* __restrict__ hs1, float* __restrict__ hs2,
    float* __restrict__ out)
{
  extern __shared__ char smem[];
  float*          bufB  = (float*)(smem + OFF_BUFB);
  unsigned short* csr   = (unsigned short*)(smem + OFF_CSR);
  unsigned short* offs  = (unsigned short*)(smem + OFF_OFFS);
  unsigned int*   wt    = (unsigned int*)(smem + OFF_WT);
  unsigned int*   cur   = (unsigned int*)(smem + OFF_CUR);
  unsigned int*   dcnt  = (unsigned int*)(smem + OFF_DCNT);
  float*          nrm   = (float*)(smem + OFF_NRM);
  float*          lin3S = (float*)(smem + OFF_L3);
  float*          keyA  = (float*)(smem + OFF_KEY);
  unsigned int*   idxA  = (unsigned int*)(smem + OFF_IDX);
  float*          featS = bufB;

  const int g    = blockIdx.x;
  const int tid  = threadIdx.x;
  const int lane = tid & 63;
  const int wv   = __builtin_amdgcn_readfirstlane(tid >> 6);   // 0..15, wave-uniform
  const int half = __builtin_amdgcn_readfirstlane(tid >> 9);   // 0/1, wave-uniform
  const int v    = tid & 511;                                  // node
  const int nb   = g * NP;
  const size_t gb = (size_t)g * (NP * 32);

  // ---------- phase 0: zero counters ----------
  if (tid < 512) { cur[tid] = 0u; dcnt[tid] = 0u; }
  __syncthreads();

  // ---------- phase 1: load edges (regs), packed deg counts ----------
  int es[8], ed[8];
  {
    const int eb = g * EPG;
#pragma unroll
    for (int i = 0; i < 8; i++) {
      const int e = eb + tid + i * 1024;
      es[i] = esrc[e] - nb;
      ed[i] = edst[e] - nb;
    }
#pragma unroll
    for (int i = 0; i < 8; i++) {
      atomicAdd(&dcnt[es[i]], 1u);        // out-degree (low 16)
      atomicAdd(&dcnt[ed[i]], 65536u);    // in-degree  (high 16)
    }
  }
  __syncthreads();

  // ---------- phase 2: norm; wave-shuffle scan of in-degree -> offs ----------
  unsigned c_scan = 0;
  if (tid < 512) {
    const unsigned cw = dcnt[tid];
    nrm[tid] = 1.0f / (float)((cw & 0xFFFFu) + 1u);
    c_scan = cw >> 16;
    for (int d = 1; d < 64; d <<= 1) {
      const unsigned t = __shfl_up(c_scan, (unsigned)d, 64);
      if (lane >= d) c_scan += t;
    }
    if (lane == 63) wt[wv] = c_scan;
  }
  __syncthreads();
  if (tid < 512) {
    unsigned base = 0;
    for (int w = 0; w < wv; w++) base += wt[w];
    offs[tid + 1] = (unsigned short)(base + c_scan);
    if (tid == 0) offs[0] = 0;
  }
  __syncthreads();

  // ---------- phase 3: fill CSR (src bucketed by dst) ----------
#pragma unroll
  for (int i = 0; i < 8; i++) {
    const unsigned pos = (unsigned)offs[ed[i]] + atomicAdd(&cur[ed[i]], 1u);
    csr[pos] = (unsigned short)es[i];
  }
  __syncthreads();

  // ---------- phase 4: lin0 (2 threads/node, 16 out-ch each; W scalar) ----------
  {
    const float* xr = x + (size_t)(nb + v) * FDIM;
    float acc[16];
#pragma unroll
    for (int c = 0; c < 16; c++) acc[c] = b0[half * 16 + c];
    for (int kb = 0; kb < 4; kb++) {
      float4 xv[8];
      const float4* xq = (const float4*)(xr + kb * 32);
#pragma unroll
      for (int j = 0; j < 8; j++) xv[j] = xq[j];
#pragma unroll
      for (int c = 0; c < 16; c++) {
        const float* wr = W0 + (size_t)(half * 16 + c) * FDIM + kb * 32;
        float a = acc[c];
#pragma unroll
        for (int j = 0; j < 8; j++) {
          a = fmaf(xv[j].x, wr[j*4+0], a);
          a = fmaf(xv[j].y, wr[j*4+1], a);
          a = fmaf(xv[j].z, wr[j*4+2], a);
          a = fmaf(xv[j].w, wr[j*4+3], a);
        }
        acc[c] = a;
      }
    }
    float4* br = (float4*)(bufB + v * STB + half * 16);
#pragma unroll
    for (int j = 0; j < 4; j++)
      br[j] = make_float4(acc[j*4+0], acc[j*4+1], acc[j*4+2], acc[j*4+3]);
  }
  __syncthreads();

  // aggregate own half (16 ch): h = tanh(nrm * (self + sum_neigh))
  float h[16];
  auto do_agg = [&]() {
    float4 A0, A1, A2, A3;
    const float4* sr = (const float4*)(bufB + v * STB + half * 16);
    A0 = sr[0]; A1 = sr[1]; A2 = sr[2]; A3 = sr[3];
    const int e0 = offs[v], e1 = offs[v + 1];
    for (int e = e0; e < e1; e++) {
      const int s = csr[e];
      const float4* rb = (const float4*)(bufB + s * STB + half * 16);
      const float4 r0 = rb[0], r1 = rb[1], r2 = rb[2], r3 = rb[3];
      A0.x += r0.x; A0.y += r0.y; A0.z += r0.z; A0.w += r0.w;
      A1.x += r1.x; A1.y += r1.y; A1.z += r1.z; A1.w += r1.w;
      A2.x += r2.x; A2.y += r2.y; A2.z += r2.z; A2.w += r2.w;
      A3.x += r3.x; A3.y += r3.y; A3.z += r3.z; A3.w += r3.w;
    }
    const float nv = nrm[v];
    h[0]=tanhf(A0.x*nv); h[1]=tanhf(A0.y*nv); h[2]=tanhf(A0.z*nv); h[3]=tanhf(A0.w*nv);
    h[4]=tanhf(A1.x*nv); h[5]=tanhf(A1.y*nv); h[6]=tanhf(A1.z*nv); h[7]=tanhf(A1.w*nv);
    h[8]=tanhf(A2.x*nv); h[9]=tanhf(A2.y*nv); h[10]=tanhf(A2.z*nv); h[11]=tanhf(A2.w*nv);
    h[12]=tanhf(A3.x*nv); h[13]=tanhf(A3.y*nv); h[14]=tanhf(A3.z*nv); h[15]=tanhf(A3.w*nv);
  };

  // write own half of h into bufB row v
  auto put_h = [&]() {
    float4* br = (float4*)(bufB + v * STB + half * 16);
#pragma unroll
    for (int j = 0; j < 4; j++)
      br[j] = make_float4(h[j*4+0], h[j*4+1], h[j*4+2], h[j*4+3]);
  };

  // coalesced [ch][node] spill of own 16 channels
  auto spill = [&](float* dst) {
#pragma unroll
    for (int c = 0; c < 16; c++)
      dst[gb + (size_t)(half * 16 + c) * 512 + v] = h[c];
  };

  // lin: read full row (32) from bufB, produce own 16 out-ch (W rows contiguous scalar)
  auto do_lin = [&](const float* __restrict__ W, const float* __restrict__ b) {
    float hf[32];
    const float4* rr = (const float4*)(bufB + v * STB);
#pragma unroll
    for (int j = 0; j < 8; j++) {
      const float4 t = rr[j];
      hf[j*4+0]=t.x; hf[j*4+1]=t.y; hf[j*4+2]=t.z; hf[j*4+3]=t.w;
    }
    __syncthreads();   // all row reads done before rewrite
    float acc[16];
#pragma unroll
    for (int c = 0; c < 16; c++) {
      const int C = half * 16 + c;
      const float* wr = W + C * 32;
      float a = b[C];
#pragma unroll
      for (int j = 0; j < 32; j++) a = fmaf(hf[j], wr[j], a);
      acc[c] = a;
    }
    float4* br = (float4*)(bufB + v * STB + half * 16);
#pragma unroll
    for (int j = 0; j < 4; j++)
      br[j] = make_float4(acc[j*4+0], acc[j*4+1], acc[j*4+2], acc[j*4+3]);
    __syncthreads();   // rows complete
  };

  // ---------- layers ----------
  do_agg();            // h1
  __syncthreads();
  put_h(); spill(hs1);
  __syncthreads();
  do_lin(W1, b1);
  do_agg();            // h2
  __syncthreads();
  put_h(); spill(hs2);
  __syncthreads();
  do_lin(W2, b2);
  do_agg();            // h3
  __syncthreads();
  put_h();             // h3 stays in bufB
  __syncthreads();

  // ---------- layer 3 (1 ch, double acc — sort key) ----------
  if (tid < 512) {
    const float4* rr = (const float4*)(bufB + tid * STB);
    double a = (double)b3[0];
#pragma unroll
    for (int j = 0; j < 8; j++) {
      const float4 t = rr[j];
      a = fma((double)t.x, (double)W3[j*4+0], a);
      a = fma((double)t.y, (double)W3[j*4+1], a);
      a = fma((double)t.z, (double)W3[j*4+2], a);
      a = fma((double)t.w, (double)W3[j*4+3], a);
    }
    lin3S[tid] = (float)a;
  }
  __syncthreads();
  float h4 = 0.f;
  if (tid < 512) {
    double a = (double)lin3S[tid];
    const int e0 = offs[tid], e1 = offs[tid + 1];
    for (int e = e0; e < e1; e++) a += (double)lin3S[csr[e]];
    a *= (double)nrm[tid];
    h4 = tanhf((float)a);
  }
  __syncthreads();     // csr reads done; keyA/idxA may overlay csr
  if (tid < 512) { keyA[tid] = h4; idxA[tid] = (unsigned)tid; }

  // ---------- bitonic sort: desc by key, asc index (stable argsort of -g) ----------
  for (int k = 2; k <= NP; k <<= 1) {
    for (int j = k >> 1; j > 0; j >>= 1) {
      __syncthreads();
      if (tid < 512) {
        const int i = tid;
        const int l = i ^ j;
        if (l > i) {
          const float    ki = keyA[i], kl = keyA[l];
          const unsigned ii = idxA[i], il = idxA[l];
          const bool iBeforeL = (ki > kl) || (ki == kl && ii < il);
          const bool doSwap = ((i & k) == 0) ? (!iBeforeL) : iBeforeL;
          if (doSwap) {
            keyA[i] = kl; keyA[l] = ki;
            idxA[i] = il; idxA[l] = ii;
          }
        }
      }
    }
  }
  __syncthreads();

  // ---------- gather top-64 into featS [dim][node] (overlays bufB) ----------
  {
    const int k = tid >> 4, t = tid & 15;   // 64 nodes x 16 threads
    const int node = (int)idxA[k];
    float vals[7];
#pragma unroll
    for (int m = 0; m < 7; m++) {
      const int d = t + 16 * m;
      float val = 0.f;
      if (d < 32)       val = hs1[gb + (size_t)d * 512 + node];
      else if (d < 64)  val = hs2[gb + (size_t)(d - 32) * 512 + node];
      else if (d < 96)  val = bufB[node * STB + (d - 64)];
      else if (d == 96) val = keyA[k];
      vals[m] = val;
    }
    __syncthreads();   // all bufB(h3) reads done before featS overlay writes
#pragma unroll
    for (int m = 0; m < 7; m++) {
      const int d = t + 16 * m;
      if (d < 97) featS[d * 64 + k] = vals[m];
    }
  }
  __syncthreads();

  // ---------- conv1 (per-node linear over 97), wave = 1 channel ----------
  {
    float* c1s = bufB + FO_C1;
    const int ch = wv;           // 0..15
    double a = (double)c1b[ch];
    const float* wr = c1w + ch * 97;
    for (int d = 0; d < 97; d++)
      a = fma((double)featS[d * 64 + lane], (double)wr[d], a);
    c1s[ch * 64 + lane] = fmaxf((float)a, 0.f);
  }
  __syncthreads();

  // ---------- maxpool(2,2) ----------
  if (tid < 512) {
    float* c1s = bufB + FO_C1;
    float* ps  = bufB + FO_P;
    const int o = tid >> 5, jj = tid & 31;
    ps[o * 32 + jj] = fmaxf(c1s[o * 64 + 2 * jj], c1s[o * 64 + 2 * jj + 1]);
  }
  __syncthreads();

  // ---------- conv2 (k=5, valid): wave = 2 out channels ----------
  {
    float* ps  = bufB + FO_P;
    float* c2s = bufB + FO_C2;
    const int o = wv;            // and o+16
    if (lane < 28) {
      double a0 = 0., a1 = 0.;
      for (int i = 0; i < 16; i++) {
#pragma unroll
        for (int r = 0; r < 5; r++) {
          const double pv = (double)ps[i * 32 + lane + r];
          a0 = fma(pv, (double)c2w[((o     ) * 16 + i) * 5 + r], a0);
          a1 = fma(pv, (double)c2w[((o + 16) * 16 + i) * 5 + r], a1);
        }
      }
      c2s[(o     ) * 28 + lane] = fmaxf((float)(a0 + (double)c2b[o     ]), 0.f);
      c2s[(o + 16) * 28 + lane] = fmaxf((float)(a1 + (double)c2b[o + 16]), 0.f);
    }
  }
  __syncthreads();

  // ---------- d1: 896 -> 128 relu; wave computes 8 outputs ----------
  {
    float* c2s  = bufB + FO_C2;
    float* hids = bufB + FO_HID;
    float fl[14];
#pragma unroll
    for (int j = 0; j < 14; j++) fl[j] = c2s[lane + j * 64];
    for (int hh = 0; hh < 8; hh++) {
      const int hI = wv * 8 + hh;
      const float* wr = d1w + (size_t)hI * 896;
      double a = 0.;
#pragma unroll
      for (int j = 0; j < 14; j++) a = fma((double)fl[j], (double)wr[lane + j * 64], a);
#pragma unroll
      for (int m = 32; m > 0; m >>= 1) a += __shfl_xor(a, m, 64);
      if (lane == 0) hids[hI] = fmaxf((float)(a + (double)d1b[hI]), 0.f);
    }
  }
  __syncthreads();

  // ---------- d2: 128 -> 10 ----------
  if (tid < 10) {
    const float* hids = bufB + FO_HID;
    const float* wr = d2w + tid * 128;
    double a = (double)d2b[tid];
#pragma unroll 8
    for (int hh = 0; hh < 128; hh++) a = fma((double)hids[hh], (double)wr[hh], a);
    out[g * 10 + tid] = (float)a;
  }
}

extern "C" void kernel_launch(void* const* d_in, const int* in_sizes, int n_in,
                              void* d_out, int out_size, void* d_ws, size_t ws_size,
                              hipStream_t stream) {
  const float* x   = (const float*)d_in[0];
  const float* W0  = (const float*)d_in[1];
  const float* b0  = (const float*)d_in[2];
  const float* W1  = (const float*)d_in[3];
  const float* b1  = (const float*)d_in[4];
  const float* W2  = (const float*)d_in[5];
  const float* b2  = (const float*)d_in[6];
  const float* W3  = (const float*)d_in[7];
  const float* b3  = (const float*)d_in[8];
  const float* c1w = (const float*)d_in[9];
  const float* c1b = (const float*)d_in[10];
  const float* c2w = (const float*)d_in[11];
  const float* c2b = (const float*)d_in[12];
  const float* d1w = (const float*)d_in[13];
  const float* d1b = (const float*)d_in[14];
  const float* d2w = (const float*)d_in[15];
  const float* d2b = (const float*)d_in[16];
  const int* esrc  = (const int*)d_in[17];
  const int* edst  = (const int*)d_in[18];

  float* hs1 = (float*)d_ws;                       // 256*512*32 f32 = 16 MB
  float* hs2 = hs1 + (size_t)NG * NP * 32;         // +16 MB
  float* outp = (float*)d_out;

  hipFuncSetAttribute(reinterpret_cast<const void*>(dgcnn_fused),
                      hipFuncAttributeMaxDynamicSharedMemorySize, SMEM_SZ);
  dgcnn_fused<<<NG, 1024, SMEM_SZ, stream>>>(x, W0, b0, W1, b1, W2, b2, W3, b3,
                                             c1w, c1b, c2w, c2b, d1w, d1b, d2w, d2b,
                                             esrc, edst, hs1, hs2, outp);
}

// Round 4
// 279.470 us; speedup vs baseline: 1.2545x; 1.2014x over previous
//
#include <hip/hip_runtime.h>

#define NG   256   // graphs (= grid)
#define NP   512   // nodes per graph
#define EPG  8192  // edges per graph
#define FDIM 128
#define STB  36    // bufB stride (floats): 144 B, 16B-aligned; random-row starts spread 8 bank-groups

// ---- LDS layout (bytes) ----
#define OFF_STAGE 0                        // x chunk stage: 512 rows x 128 B = 65536
#define OFF_BUFB  65536                    // f32[512*36] = 73728 -> ends 139264
#define OFF_CSR   139264                   // u16[8192] = 16384 -> 155648
#define OFF_OFFS  155648                   // u16[513] -> 1032  -> 156680
#define OFF_WT    156680                   // u32[8] = 32       -> 156712
#define OFF_CUR   156712                   // u32[512] = 2048   -> 158760 (lin3S overlay later)
#define OFF_DCNT  158760                   // u32[512] = 2048   -> 160808
#define OFF_NRM   160808                   // f32[512] = 2048   -> 162856
#define SMEM_SZ   162856                   // <= 163840

// overlays
#define OFF_KEY  OFF_CSR                   // f32[512] (csr dead after layer-3 agg)
#define OFF_IDX  (OFF_CSR + 2048)          // u32[512]
#define OFF_L3   OFF_CUR                   // f32[512] (cursors dead after CSR build)
// tail arrays live in the dead stage region (float offsets from stage base)
#define FO_FEAT 0                          // f32[97*64] = 6208 floats
#define FO_C1   6208                       // f32[16*64]
#define FO_P    7232                       // f32[16*32]
#define FO_C2   7744                       // f32[896]
#define FO_HID  8640                       // f32[128]

__global__ __launch_bounds__(1024, 4) void dgcnn_fused(
    const float* __restrict__ x,
    const float* __restrict__ W0, const float* __restrict__ b0,
    const float* __restrict__ W1, const float* __restrict__ b1,
    const float* __restrict__ W2, const float* __restrict__ b2,
    const float* __restrict__ W3, const float* __restrict__ b3,
    const float* __restrict__ c1w, const float* __restrict__ c1b,
    const float* __restrict__ c2w, const float* __restrict__ c2b,
    const float* __restrict__ d1w, const float* __restrict__ d1b,
    const float* __restrict__ d2w, const float* __restrict__ d2b,
    const int* __restrict__ esrc, const int* __restrict__ edst,
    float* __restrict__ hs1, float* __restrict__ hs2,
    float* __restrict__ out)
{
  extern __shared__ char smem[];
  float*          stageF = (float*)(smem + OFF_STAGE);
  float*          bufB  = (float*)(smem + OFF_BUFB);
  unsigned short* csr   = (unsigned short*)(smem + OFF_CSR);
  unsigned short* offs  = (unsigned short*)(smem + OFF_OFFS);
  unsigned int*   wt    = (unsigned int*)(smem + OFF_WT);
  unsigned int*   cur   = (unsigned int*)(smem + OFF_CUR);
  unsigned int*   dcnt  = (unsigned int*)(smem + OFF_DCNT);
  float*          nrm   = (float*)(smem + OFF_NRM);
  float*          lin3S = (float*)(smem + OFF_L3);
  float*          keyA  = (float*)(smem + OFF_KEY);
  unsigned int*   idxA  = (unsigned int*)(smem + OFF_IDX);

  const int g    = blockIdx.x;
  const int tid  = threadIdx.x;
  const int lane = tid & 63;
  const int wv   = __builtin_amdgcn_readfirstlane(tid >> 6);   // 0..15, wave-uniform
  const int half = __builtin_amdgcn_readfirstlane(tid >> 9);   // 0/1, wave-uniform
  const int v    = tid & 511;                                  // node
  const int nb   = g * NP;
  const size_t gb = (size_t)g * (NP * 32);

  // x chunk loaders: chunk kc = dims [kc*32, kc*32+32) for all 512 rows.
  // thread's 4 slices: row = (tid>>3) + it*128, grp = tid&7 (16 B within the 128 B chunk-row)
  const int ldRow0 = tid >> 3;
  const int ldGrp  = tid & 7;
  const int ldSwz  = (ldGrp ^ (ldRow0 & 7)) * 16;   // row&7 invariant under +128
  auto load_chunk = [&](int kc, float4* xr) {
    const float* base = x + (size_t)nb * FDIM + kc * 32 + ldGrp * 4;
#pragma unroll
    for (int it = 0; it < 4; it++)
      xr[it] = *(const float4*)(base + (size_t)(ldRow0 + it * 128) * FDIM);
  };
  auto store_chunk = [&](const float4* xr) {
#pragma unroll
    for (int it = 0; it < 4; it++)
      *(float4*)(smem + OFF_STAGE + (ldRow0 + it * 128) * 128 + ldSwz) = xr[it];
  };

  // issue chunk-0 x loads before anything else (latency hidden behind CSR build)
  float4 xr[4], xr2[4];
  load_chunk(0, xr);

  // ---------- phase 0: zero counters ----------
  if (tid < 512) { cur[tid] = 0u; dcnt[tid] = 0u; }
  __syncthreads();

  // ---------- phase 1: edges via int4 (regs), packed deg counts ----------
  int es[8], ed[8];
  {
    const int eb = g * EPG;
    const int4* s4 = (const int4*)(esrc + eb);
    const int4* d4 = (const int4*)(edst + eb);
    const int4 sa = s4[tid], sb = s4[tid + 1024];
    const int4 da = d4[tid], db = d4[tid + 1024];
    es[0]=sa.x-nb; es[1]=sa.y-nb; es[2]=sa.z-nb; es[3]=sa.w-nb;
    es[4]=sb.x-nb; es[5]=sb.y-nb; es[6]=sb.z-nb; es[7]=sb.w-nb;
    ed[0]=da.x-nb; ed[1]=da.y-nb; ed[2]=da.z-nb; ed[3]=da.w-nb;
    ed[4]=db.x-nb; ed[5]=db.y-nb; ed[6]=db.z-nb; ed[7]=db.w-nb;
#pragma unroll
    for (int i = 0; i < 8; i++) {
      atomicAdd(&dcnt[es[i]], 1u);        // out-degree (low 16)
      atomicAdd(&dcnt[ed[i]], 65536u);    // in-degree  (high 16)
    }
  }
  __syncthreads();

  // ---------- phase 2: norm; wave-shuffle scan of in-degree -> offs ----------
  unsigned c_scan = 0;
  if (tid < 512) {
    const unsigned cw = dcnt[tid];
    nrm[tid] = 1.0f / (float)((cw & 0xFFFFu) + 1u);
    c_scan = cw >> 16;
    for (int d = 1; d < 64; d <<= 1) {
      const unsigned t = __shfl_up(c_scan, (unsigned)d, 64);
      if (lane >= d) c_scan += t;
    }
    if (lane == 63) wt[wv] = c_scan;
  }
  __syncthreads();
  if (tid < 512) {
    unsigned base = 0;
    for (int w = 0; w < wv; w++) base += wt[w];
    offs[tid + 1] = (unsigned short)(base + c_scan);
    if (tid == 0) offs[0] = 0;
  }
  __syncthreads();

  // ---------- phase 3: fill CSR (src bucketed by dst) ----------
#pragma unroll
  for (int i = 0; i < 8; i++) {
    const unsigned pos = (unsigned)offs[ed[i]] + atomicAdd(&cur[ed[i]], 1u);
    csr[pos] = (unsigned short)es[i];
  }

  // ---------- phase 4: lin0 via LDS-staged x chunks ----------
  float acc0[16];
#pragma unroll
  for (int c = 0; c < 16; c++) acc0[c] = b0[half * 16 + c];
  const char* rowp = smem + OFF_STAGE + v * 128;
  const int vswz = v & 7;
  for (int kc = 0; kc < 4; kc++) {
    __syncthreads();                       // stage free / CSR done
    store_chunk(xr);
    if (kc < 3) load_chunk(kc + 1, xr2);
    __syncthreads();
#pragma unroll
    for (int jg = 0; jg < 8; jg++) {
      const float4 t = *(const float4*)(rowp + ((jg ^ vswz) * 16));
#pragma unroll
      for (int c = 0; c < 16; c++) {
        const float* wr = W0 + (size_t)(half * 16 + c) * FDIM + kc * 32 + jg * 4;
        acc0[c] = fmaf(t.x, wr[0], acc0[c]);
        acc0[c] = fmaf(t.y, wr[1], acc0[c]);
        acc0[c] = fmaf(t.z, wr[2], acc0[c]);
        acc0[c] = fmaf(t.w, wr[3], acc0[c]);
      }
    }
#pragma unroll
    for (int it = 0; it < 4; it++) xr[it] = xr2[it];
  }
  {
    float4* br = (float4*)(bufB + v * STB + half * 16);
#pragma unroll
    for (int j = 0; j < 4; j++)
      br[j] = make_float4(acc0[j*4+0], acc0[j*4+1], acc0[j*4+2], acc0[j*4+3]);
  }
  __syncthreads();

  // aggregate own half (16 ch): h = tanh(nrm * (self + sum_neigh)); unroll-2 edge loop
  float h[16];
  auto do_agg = [&]() {
    float4 A0, A1, A2, A3;
    const float4* sr = (const float4*)(bufB + v * STB + half * 16);
    A0 = sr[0]; A1 = sr[1]; A2 = sr[2]; A3 = sr[3];
    const int e0 = offs[v], e1 = offs[v + 1];
    int e = e0;
    for (; e + 1 < e1; e += 2) {
      const int s0 = csr[e], s1 = csr[e + 1];
      const float4* rb0 = (const float4*)(bufB + s0 * STB + half * 16);
      const float4* rb1 = (const float4*)(bufB + s1 * STB + half * 16);
      const float4 p0 = rb0[0], p1 = rb0[1], p2 = rb0[2], p3 = rb0[3];
      const float4 q0 = rb1[0], q1 = rb1[1], q2 = rb1[2], q3 = rb1[3];
      A0.x += p0.x + q0.x; A0.y += p0.y + q0.y; A0.z += p0.z + q0.z; A0.w += p0.w + q0.w;
      A1.x += p1.x + q1.x; A1.y += p1.y + q1.y; A1.z += p1.z + q1.z; A1.w += p1.w + q1.w;
      A2.x += p2.x + q2.x; A2.y += p2.y + q2.y; A2.z += p2.z + q2.z; A2.w += p2.w + q2.w;
      A3.x += p3.x + q3.x; A3.y += p3.y + q3.y; A3.z += p3.z + q3.z; A3.w += p3.w + q3.w;
    }
    if (e < e1) {
      const int s = csr[e];
      const float4* rb = (const float4*)(bufB + s * STB + half * 16);
      const float4 r0 = rb[0], r1 = rb[1], r2 = rb[2], r3 = rb[3];
      A0.x += r0.x; A0.y += r0.y; A0.z += r0.z; A0.w += r0.w;
      A1.x += r1.x; A1.y += r1.y; A1.z += r1.z; A1.w += r1.w;
      A2.x += r2.x; A2.y += r2.y; A2.z += r2.z; A2.w += r2.w;
      A3.x += r3.x; A3.y += r3.y; A3.z += r3.z; A3.w += r3.w;
    }
    const float nv = nrm[v];
    h[0]=tanhf(A0.x*nv); h[1]=tanhf(A0.y*nv); h[2]=tanhf(A0.z*nv); h[3]=tanhf(A0.w*nv);
    h[4]=tanhf(A1.x*nv); h[5]=tanhf(A1.y*nv); h[6]=tanhf(A1.z*nv); h[7]=tanhf(A1.w*nv);
    h[8]=tanhf(A2.x*nv); h[9]=tanhf(A2.y*nv); h[10]=tanhf(A2.z*nv); h[11]=tanhf(A2.w*nv);
    h[12]=tanhf(A3.x*nv); h[13]=tanhf(A3.y*nv); h[14]=tanhf(A3.z*nv); h[15]=tanhf(A3.w*nv);
  };

  auto put_h = [&]() {
    float4* br = (float4*)(bufB + v * STB + half * 16);
#pragma unroll
    for (int j = 0; j < 4; j++)
      br[j] = make_float4(h[j*4+0], h[j*4+1], h[j*4+2], h[j*4+3]);
  };

  auto spill = [&](float* dst) {
#pragma unroll
    for (int c = 0; c < 16; c++)
      dst[gb + (size_t)(half * 16 + c) * 512 + v] = h[c];
  };

  auto do_lin = [&](const float* __restrict__ W, const float* __restrict__ b) {
    float hf[32];
    const float4* rr = (const float4*)(bufB + v * STB);
#pragma unroll
    for (int j = 0; j < 8; j++) {
      const float4 t = rr[j];
      hf[j*4+0]=t.x; hf[j*4+1]=t.y; hf[j*4+2]=t.z; hf[j*4+3]=t.w;
    }
    __syncthreads();   // all row reads done before rewrite
    float acc[16];
#pragma unroll
    for (int c = 0; c < 16; c++) {
      const int C = half * 16 + c;
      const float* wr = W + C * 32;
      float a = b[C];
#pragma unroll
      for (int j = 0; j < 32; j++) a = fmaf(hf[j], wr[j], a);
      acc[c] = a;
    }
    float4* br = (float4*)(bufB + v * STB + half * 16);
#pragma unroll
    for (int j = 0; j < 4; j++)
      br[j] = make_float4(acc[j*4+0], acc[j*4+1], acc[j*4+2], acc[j*4+3]);
    __syncthreads();   // rows complete
  };

  // ---------- layers ----------
  do_agg();            // h1
  __syncthreads();
  put_h(); spill(hs1);
  __syncthreads();
  do_lin(W1, b1);
  do_agg();            // h2
  __syncthreads();
  put_h(); spill(hs2);
  __syncthreads();
  do_lin(W2, b2);
  do_agg();            // h3
  __syncthreads();
  put_h();             // h3 stays in bufB
  __syncthreads();

  // ---------- layer 3 (1 ch, double acc — sort key) ----------
  if (tid < 512) {
    const float4* rr = (const float4*)(bufB + tid * STB);
    double a = (double)b3[0];
#pragma unroll
    for (int j = 0; j < 8; j++) {
      const float4 t = rr[j];
      a = fma((double)t.x, (double)W3[j*4+0], a);
      a = fma((double)t.y, (double)W3[j*4+1], a);
      a = fma((double)t.z, (double)W3[j*4+2], a);
      a = fma((double)t.w, (double)W3[j*4+3], a);
    }
    lin3S[tid] = (float)a;
  }
  __syncthreads();
  float h4 = 0.f;
  if (tid < 512) {
    double a = (double)lin3S[tid];
    const int e0 = offs[tid], e1 = offs[tid + 1];
    for (int e = e0; e < e1; e++) a += (double)lin3S[csr[e]];
    a *= (double)nrm[tid];
    h4 = tanhf((float)a);
  }
  __syncthreads();     // csr reads done; keyA/idxA may overlay csr
  if (tid < 512) { keyA[tid] = h4; idxA[tid] = (unsigned)tid; }

  // ---------- bitonic sort: desc by key, asc index (stable argsort of -g) ----------
  for (int k = 2; k <= NP; k <<= 1) {
    for (int j = k >> 1; j > 0; j >>= 1) {
      __syncthreads();
      if (tid < 512) {
        const int i = tid;
        const int l = i ^ j;
        if (l > i) {
          const float    ki = keyA[i], kl = keyA[l];
          const unsigned ii = idxA[i], il = idxA[l];
          const bool iBeforeL = (ki > kl) || (ki == kl && ii < il);
          const bool doSwap = ((i & k) == 0) ? (!iBeforeL) : iBeforeL;
          if (doSwap) {
            keyA[i] = kl; keyA[l] = ki;
            idxA[i] = il; idxA[l] = ii;
          }
        }
      }
    }
  }
  __syncthreads();

  // ---------- gather top-64 into featS [dim][node] (stage region, dead) ----------
  {
    float* featS = stageF + FO_FEAT;
    const int k = tid >> 4, t = tid & 15;   // 64 nodes x 16 threads
    const int node = (int)idxA[k];
#pragma unroll
    for (int m = 0; m < 7; m++) {
      const int d = t + 16 * m;
      float val;
      if (d < 32)       val = hs1[gb + (size_t)d * 512 + node];
      else if (d < 64)  val = hs2[gb + (size_t)(d - 32) * 512 + node];
      else if (d < 96)  val = bufB[node * STB + (d - 64)];
      else              val = keyA[k];
      if (d < 97) featS[d * 64 + k] = val;
    }
  }
  __syncthreads();

  // ---------- conv1 (per-node linear over 97), wave = 1 channel ----------
  {
    const float* featS = stageF + FO_FEAT;
    float* c1s = stageF + FO_C1;
    const int ch = wv;           // 0..15
    double a = (double)c1b[ch];
    const float* wr = c1w + ch * 97;
    for (int d = 0; d < 97; d++)
      a = fma((double)featS[d * 64 + lane], (double)wr[d], a);
    c1s[ch * 64 + lane] = fmaxf((float)a, 0.f);
  }
  __syncthreads();

  // ---------- maxpool(2,2) ----------
  if (tid < 512) {
    const float* c1s = stageF + FO_C1;
    float* ps  = stageF + FO_P;
    const int o = tid >> 5, jj = tid & 31;
    ps[o * 32 + jj] = fmaxf(c1s[o * 64 + 2 * jj], c1s[o * 64 + 2 * jj + 1]);
  }
  __syncthreads();

  // ---------- conv2 (k=5, valid): wave = 2 out channels ----------
  {
    const float* ps  = stageF + FO_P;
    float* c2s = stageF + FO_C2;
    const int o = wv;            // and o+16
    if (lane < 28) {
      double a0 = 0., a1 = 0.;
      for (int i = 0; i < 16; i++) {
#pragma unroll
        for (int r = 0; r < 5; r++) {
          const double pv = (double)ps[i * 32 + lane + r];
          a0 = fma(pv, (double)c2w[((o     ) * 16 + i) * 5 + r], a0);
          a1 = fma(pv, (double)c2w[((o + 16) * 16 + i) * 5 + r], a1);
        }
      }
      c2s[(o     ) * 28 + lane] = fmaxf((float)(a0 + (double)c2b[o     ]), 0.f);
      c2s[(o + 16) * 28 + lane] = fmaxf((float)(a1 + (double)c2b[o + 16]), 0.f);
    }
  }
  __syncthreads();

  // ---------- d1: 896 -> 128 relu; wave computes 8 outputs ----------
  {
    const float* c2s  = stageF + FO_C2;
    float* hids = stageF + FO_HID;
    float fl[14];
#pragma unroll
    for (int j = 0; j < 14; j++) fl[j] = c2s[lane + j * 64];
    for (int hh = 0; hh < 8; hh++) {
      const int hI = wv * 8 + hh;
      const float* wr = d1w + (size_t)hI * 896;
      double a = 0.;
#pragma unroll
      for (int j = 0; j < 14; j++) a = fma((double)fl[j], (double)wr[lane + j * 64], a);
#pragma unroll
      for (int m = 32; m > 0; m >>= 1) a += __shfl_xor(a, m, 64);
      if (lane == 0) hids[hI] = fmaxf((float)(a + (double)d1b[hI]), 0.f);
    }
  }
  __syncthreads();

  // ---------- d2: 128 -> 10 ----------
  if (tid < 10) {
    const float* hids = stageF + FO_HID;
    const float* wr = d2w + tid * 128;
    double a = (double)d2b[tid];
#pragma unroll 8
    for (int hh = 0; hh < 128; hh++) a = fma((double)hids[hh], (double)wr[hh], a);
    out[g * 10 + tid] = (float)a;
  }
}

extern "C" void kernel_launch(void* const* d_in, const int* in_sizes, int n_in,
                              void* d_out, int out_size, void* d_ws, size_t ws_size,
                              hipStream_t stream) {
  const float* x   = (const float*)d_in[0];
  const float* W0  = (const float*)d_in[1];
  const float* b0  = (const float*)d_in[2];
  const float* W1  = (const float*)d_in[3];
  const float* b1  = (const float*)d_in[4];
  const float* W2  = (const float*)d_in[5];
  const float* b2  = (const float*)d_in[6];
  const float* W3  = (const float*)d_in[7];
  const float* b3  = (const float*)d_in[8];
  const float* c1w = (const float*)d_in[9];
  const float* c1b = (const float*)d_in[10];
  const float* c2w = (const float*)d_in[11];
  const float* c2b = (const float*)d_in[12];
  const float* d1w = (const float*)d_in[13];
  const float* d1b = (const float*)d_in[14];
  const float* d2w = (const float*)d_in[15];
  const float* d2b = (const float*)d_in[16];
  const int* esrc  = (const int*)d_in[17];
  const int* edst  = (const int*)d_in[18];

  float* hs1 = (float*)d_ws;                       // 256*512*32 f32 = 16 MB
  float* hs2 = hs1 + (size_t)NG * NP * 32;         // +16 MB
  float* outp = (float*)d_out;

  hipFuncSetAttribute(reinterpret_cast<const void*>(dgcnn_fused),
                      hipFuncAttributeMaxDynamicSharedMemorySize, SMEM_SZ);
  dgcnn_fused<<<NG, 1024, SMEM_SZ, stream>>>(x, W0, b0, W1, b1, W2, b2, W3, b3,
                                             c1w, c1b, c2w, c2b, d1w, d1b, d2w, d2b,
                                             esrc, edst, hs1, hs2, outp);
}